// Round 1
// baseline (8022.527 us; speedup 1.0000x reference)
//
#include <hip/hip_runtime.h>

#define BS    32     // batches
#define M     256    // rows
#define N     512    // cols
#define ITERS 1000
#define WPB   8      // workgroups per batch
#define RPW   32     // rows per workgroup (M / WPB)
#define BLK   256    // threads per block
#define ALPHA 0.02f
#define BETA  0.02f

// LDS layout: each 64-col chunk padded to 68 floats so that in phase B the
// 8 lanes of a b128 group (l8=0..7) land on distinct bank-quads (17*l8+k mod 8
// is a bijection over l8).
#define CH        68
#define ROWSTRIDE (8 * CH)            // 544 floats per row
#define A_FLOATS  (RPW * ROWSTRIDE)   // 17408
#define V_OFF     A_FLOATS            // v: 544 floats (padded)
#define U_OFF     (A_FLOATS + ROWSTRIDE)
#define SMEM_FLOATS (U_OFF + RPW)     // + u[32]

__device__ __forceinline__ int ldsidx(int r, int n) {
  return r * ROWSTRIDE + (n >> 6) * CH + (n & 63);
}

__global__ __launch_bounds__(BLK, 1) void pdhg_kernel(
    const float* __restrict__ A, const float* __restrict__ Bvec,
    float* __restrict__ out, float* __restrict__ pbuf,
    unsigned* __restrict__ flags)
{
  __shared__ float smem[SMEM_FLOATS];
  const int tid   = threadIdx.x;
  const int bid   = blockIdx.x;
  const int batch = bid & (BS - 1);   // consecutive bids of a batch are 32 apart
  const int slice = bid >> 5;         //  -> same XCD under round-robin dispatch
  const int row0  = slice * RPW;

  // ---- stage A slice into LDS (padded layout), coalesced float4 ----
  const float* Ag = A + (size_t)batch * M * N + (size_t)row0 * N;
  for (int i = tid; i < RPW * N / 4; i += BLK) {
    int r = i >> 7;              // 128 float4 per row
    int n = (i & 127) << 2;
    float4 a = reinterpret_cast<const float4*>(Ag)[i];
    *reinterpret_cast<float4*>(&smem[ldsidx(r, n)]) = a;
  }

  const int   r    = tid >> 3;   // phase-B row (0..31)
  const int   l8   = tid & 7;    // phase-B col chunk
  const float breg = Bvec[batch * M + row0 + r];
  float u_reg = 0.0f;            // row-owned u (replicated across the 8 lanes)
  float x0 = 0.0f, x1 = 0.0f;    // col-owned x (cols 2*tid, 2*tid+1)
  const int n0 = 2 * tid;

  float* v_s = smem + V_OFF;
  float* u_s = smem + U_OFF;

  unsigned* flg = flags + batch * WPB * 32;   // one flag per wg, 128 B apart

  const int vb = (n0 >> 6) * CH + (n0 & 63);  // padded index of col n0 (even)

  for (int it = 0; it < ITERS; ++it) {
    const int buf = it & 1;

    // ---- phase A: t = A^T u (sum of 8 partials), x/v update (col-owned) ----
    float t0 = 0.f, t1 = 0.f;
    const float* pr = pbuf + ((size_t)(buf * BS + batch) * WPB) * N + n0;
#pragma unroll
    for (int w = 0; w < WPB; ++w) {
      float2 p = *reinterpret_cast<const float2*>(pr + w * N);
      t0 += p.x; t1 += p.y;
    }
    float y0  = x0 - ALPHA * t0, y1 = x1 - ALPHA * t1;
    float xn0 = fmaxf(y0 - ALPHA, 0.f) - fmaxf(-y0 - ALPHA, 0.f);
    float xn1 = fmaxf(y1 - ALPHA, 0.f) - fmaxf(-y1 - ALPHA, 0.f);
    float v0  = 2.f * xn0 - x0, v1 = 2.f * xn1 - x1;
    x0 = xn0; x1 = xn1;

    if (it == ITERS - 1) break;   // x is final after this phase A (all wgs break)

    *reinterpret_cast<float2*>(&v_s[vb]) = make_float2(v0, v1);
    __syncthreads();

    // ---- phase B: row dots (A·v), u update (row-owned) ----
    float dot = 0.f;
    {
      const float4* A4 = reinterpret_cast<const float4*>(smem) +
                         (r * (ROWSTRIDE / 4) + l8 * (CH / 4));
      const float4* V4 = reinterpret_cast<const float4*>(v_s) + l8 * (CH / 4);
#pragma unroll
      for (int k = 0; k < 16; ++k) {
        float4 a  = A4[k];
        float4 vv = V4[k];
        dot += a.x * vv.x + a.y * vv.y + a.z * vv.z + a.w * vv.w;
      }
    }
    dot += __shfl_xor(dot, 1);
    dot += __shfl_xor(dot, 2);
    dot += __shfl_xor(dot, 4);
    u_reg += BETA * (dot - breg);
    if (l8 == 0) u_s[r] = u_reg;
    __syncthreads();

    // ---- phase C: partial p = A_slice^T u (col-owned), publish to pbuf ----
    float us[RPW];
#pragma unroll
    for (int k = 0; k < RPW / 4; ++k) {
      float4 uu = reinterpret_cast<const float4*>(u_s)[k];  // broadcast reads
      us[4*k] = uu.x; us[4*k+1] = uu.y; us[4*k+2] = uu.z; us[4*k+3] = uu.w;
    }
    float p0 = 0.f, p1 = 0.f;
    const float2* A2 = reinterpret_cast<const float2*>(smem) + (vb >> 1);
#pragma unroll
    for (int rr = 0; rr < RPW; ++rr) {
      float2 a = A2[rr * (ROWSTRIDE / 2)];
      p0 += a.x * us[rr];
      p1 += a.y * us[rr];
    }
    const int nbuf = buf ^ 1;
    *reinterpret_cast<float2*>(
        pbuf + ((size_t)(nbuf * BS + batch) * WPB + slice) * N + n0) =
        make_float2(p0, p1);

    // ---- per-batch barrier: release own flag, poll all 8 with one vec load ----
    const unsigned want = (unsigned)(it + 1);
    __syncthreads();   // drains this wg's pbuf stores (vmcnt(0) before s_barrier)
    if (tid == 0)
      __hip_atomic_store(&flg[slice * 32], want, __ATOMIC_RELEASE,
                         __HIP_MEMORY_SCOPE_AGENT);
    if (tid < WPB) {
      while (__hip_atomic_load(&flg[tid * 32], __ATOMIC_ACQUIRE,
                               __HIP_MEMORY_SCOPE_AGENT) < want) { }
    }
    __syncthreads();
  }

  // ---- epilogue: slice 0 writes x (all wgs hold identical x) ----
  if (slice == 0) {
    *reinterpret_cast<float2*>(out + (size_t)batch * N + n0) =
        make_float2(x0, x1);
  }
}

extern "C" void kernel_launch(void* const* d_in, const int* in_sizes, int n_in,
                              void* d_out, int out_size, void* d_ws, size_t ws_size,
                              hipStream_t stream) {
  const float* A = (const float*)d_in[0];
  const float* b = (const float*)d_in[1];
  float* out  = (float*)d_out;
  float* pbuf = (float*)d_ws;                         // [2][BS][WPB][N] floats
  const size_t pbytes = (size_t)2 * BS * WPB * N * sizeof(float);   // 1 MiB
  unsigned* flags = (unsigned*)((char*)d_ws + pbytes);              // 32 KiB
  const size_t zbytes = pbytes + (size_t)BS * WPB * 32 * sizeof(unsigned);

  hipMemsetAsync(d_ws, 0, zbytes, stream);   // zero iter-0 partials + flags

  void* args[] = {(void*)&A, (void*)&b, (void*)&out, (void*)&pbuf, (void*)&flags};
  hipLaunchCooperativeKernel((const void*)pdhg_kernel, dim3(BS * WPB), dim3(BLK),
                             args, 0, stream);
}

// Round 2
// 2438.775 us; speedup vs baseline: 3.2896x; 3.2896x over previous
//
#include <hip/hip_runtime.h>

#define BS    32     // batches
#define M     256    // rows
#define N     512    // cols
#define ITERS 1000
#define WPB   8      // workgroups per batch
#define RPW   32     // rows per workgroup (M / WPB)
#define BLK   256    // threads per block
#define ALPHA 0.02f
#define BETA  0.02f

// LDS layout: each 64-col chunk padded to 68 floats so that in phase B the
// 8 lanes of a b128 group (l8=0..7) land on distinct bank-quads.
#define CH        68
#define ROWSTRIDE (8 * CH)            // 544 floats per row
#define A_FLOATS  (RPW * ROWSTRIDE)   // 17408
#define V_OFF     A_FLOATS            // v: 544 floats (padded)
#define U_OFF     (A_FLOATS + ROWSTRIDE)
#define SMEM_FLOATS (U_OFF + RPW)     // + u[32]

__device__ __forceinline__ int ldsidx(int r, int n) {
  return r * ROWSTRIDE + (n >> 6) * CH + (n & 63);
}

// ---- relaxed agent-scope (sc1, L2-bypassing) 8-byte accesses ----
// No buffer_wbl2 / buffer_inv: data moves through the MALL coherence point,
// ordering provided by __syncthreads()'s vmcnt(0) drain + control dependence.
union F2U { float2 f; unsigned long long u; };

__device__ __forceinline__ void st_coh_f2(float* p, float2 v) {
  F2U c; c.f = v;
  __hip_atomic_store(reinterpret_cast<unsigned long long*>(p), c.u,
                     __ATOMIC_RELAXED, __HIP_MEMORY_SCOPE_AGENT);
}
__device__ __forceinline__ float2 ld_coh_f2(const float* p) {
  F2U c;
  c.u = __hip_atomic_load(reinterpret_cast<const unsigned long long*>(p),
                          __ATOMIC_RELAXED, __HIP_MEMORY_SCOPE_AGENT);
  return c.f;
}

__global__ __launch_bounds__(BLK, 1) void pdhg_kernel(
    const float* __restrict__ A, const float* __restrict__ Bvec,
    float* __restrict__ out, float* __restrict__ pbuf,
    unsigned* __restrict__ flags)
{
  __shared__ float smem[SMEM_FLOATS];
  const int tid   = threadIdx.x;
  const int bid   = blockIdx.x;
  const int batch = bid & (BS - 1);
  const int slice = bid >> 5;
  const int row0  = slice * RPW;

  // ---- stage A slice into LDS (padded layout), coalesced float4 ----
  const float* Ag = A + (size_t)batch * M * N + (size_t)row0 * N;
  for (int i = tid; i < RPW * N / 4; i += BLK) {
    int r = i >> 7;              // 128 float4 per row
    int n = (i & 127) << 2;
    float4 a = reinterpret_cast<const float4*>(Ag)[i];
    *reinterpret_cast<float4*>(&smem[ldsidx(r, n)]) = a;
  }

  const int   r    = tid >> 3;   // phase-B row (0..31)
  const int   l8   = tid & 7;    // phase-B col chunk
  const float breg = Bvec[batch * M + row0 + r];
  float u_reg = 0.0f;            // row-owned u (replicated across 8 lanes)
  float x0 = 0.0f, x1 = 0.0f;    // col-owned x (cols 2*tid, 2*tid+1)
  const int n0 = 2 * tid;

  float* v_s = smem + V_OFF;
  float* u_s = smem + U_OFF;

  unsigned* flg = flags + batch * WPB * 32;   // one flag per wg, 128 B apart

  const int vb = (n0 >> 6) * CH + (n0 & 63);  // padded index of col n0 (even)

  for (int it = 0; it < ITERS; ++it) {
    const int buf = it & 1;

    // ---- phase A: t = A^T u (sum of 8 partials), x/v update (col-owned) ----
    float t0 = 0.f, t1 = 0.f;
    float* pr = pbuf + ((size_t)(buf * BS + batch) * WPB) * N + n0;
#pragma unroll
    for (int w = 0; w < WPB; ++w) {
      float2 p = ld_coh_f2(pr + w * N);
      t0 += p.x; t1 += p.y;
    }
    float y0  = x0 - ALPHA * t0, y1 = x1 - ALPHA * t1;
    float xn0 = fmaxf(y0 - ALPHA, 0.f) - fmaxf(-y0 - ALPHA, 0.f);
    float xn1 = fmaxf(y1 - ALPHA, 0.f) - fmaxf(-y1 - ALPHA, 0.f);
    float v0  = 2.f * xn0 - x0, v1 = 2.f * xn1 - x1;
    x0 = xn0; x1 = xn1;

    if (it == ITERS - 1) break;   // x is final after this phase A (all wgs)

    *reinterpret_cast<float2*>(&v_s[vb]) = make_float2(v0, v1);
    __syncthreads();

    // ---- phase B: row dots (A·v), u update (row-owned) ----
    float dot = 0.f;
    {
      const float4* A4 = reinterpret_cast<const float4*>(smem) +
                         (r * (ROWSTRIDE / 4) + l8 * (CH / 4));
      const float4* V4 = reinterpret_cast<const float4*>(v_s) + l8 * (CH / 4);
#pragma unroll
      for (int k = 0; k < 16; ++k) {
        float4 a  = A4[k];
        float4 vv = V4[k];
        dot += a.x * vv.x + a.y * vv.y + a.z * vv.z + a.w * vv.w;
      }
    }
    dot += __shfl_xor(dot, 1);
    dot += __shfl_xor(dot, 2);
    dot += __shfl_xor(dot, 4);
    u_reg += BETA * (dot - breg);
    if (l8 == 0) u_s[r] = u_reg;
    __syncthreads();

    // ---- phase C: partial p = A_slice^T u (col-owned), publish to pbuf ----
    float us[RPW];
#pragma unroll
    for (int k = 0; k < RPW / 4; ++k) {
      float4 uu = reinterpret_cast<const float4*>(u_s)[k];  // broadcast reads
      us[4*k] = uu.x; us[4*k+1] = uu.y; us[4*k+2] = uu.z; us[4*k+3] = uu.w;
    }
    float p0 = 0.f, p1 = 0.f;
    const float2* A2 = reinterpret_cast<const float2*>(smem) + (vb >> 1);
#pragma unroll
    for (int rr = 0; rr < RPW; ++rr) {
      float2 a = A2[rr * (ROWSTRIDE / 2)];
      p0 += a.x * us[rr];
      p1 += a.y * us[rr];
    }
    const int nbuf = buf ^ 1;
    st_coh_f2(pbuf + ((size_t)(nbuf * BS + batch) * WPB + slice) * N + n0,
              make_float2(p0, p1));

    // ---- per-batch barrier ----
    // __syncthreads drains vmcnt(0): the sc1 stores above are acked at the
    // coherence point before any thread can store the flag.
    const unsigned want = (unsigned)(it + 1);
    __syncthreads();
    if (tid == 0)
      __hip_atomic_store(&flg[slice * 32], want, __ATOMIC_RELAXED,
                         __HIP_MEMORY_SCOPE_AGENT);
    if (tid < WPB) {
      while (__hip_atomic_load(&flg[tid * 32], __ATOMIC_RELAXED,
                               __HIP_MEMORY_SCOPE_AGENT) < want) { }
    }
    __atomic_signal_fence(__ATOMIC_SEQ_CST);  // compiler-only fence
    __syncthreads();   // readers' phase-A loads are ordered after this
  }

  // ---- epilogue: slice 0 writes x (all wgs hold identical x) ----
  if (slice == 0) {
    *reinterpret_cast<float2*>(out + (size_t)batch * N + n0) =
        make_float2(x0, x1);
  }
}

extern "C" void kernel_launch(void* const* d_in, const int* in_sizes, int n_in,
                              void* d_out, int out_size, void* d_ws, size_t ws_size,
                              hipStream_t stream) {
  const float* A = (const float*)d_in[0];
  const float* b = (const float*)d_in[1];
  float* out  = (float*)d_out;
  float* pbuf = (float*)d_ws;                         // [2][BS][WPB][N] floats
  const size_t pbytes = (size_t)2 * BS * WPB * N * sizeof(float);   // 1 MiB
  unsigned* flags = (unsigned*)((char*)d_ws + pbytes);              // 32 KiB
  const size_t zbytes = pbytes + (size_t)BS * WPB * 32 * sizeof(unsigned);

  hipMemsetAsync(d_ws, 0, zbytes, stream);   // zero iter-0 partials + flags

  void* args[] = {(void*)&A, (void*)&b, (void*)&out, (void*)&pbuf, (void*)&flags};
  hipLaunchCooperativeKernel((const void*)pdhg_kernel, dim3(BS * WPB), dim3(BLK),
                             args, 0, stream);
}